// Round 8
// baseline (606.092 us; speedup 1.0000x reference)
//
#include <hip/hip_runtime.h>
#include <hip/hip_bf16.h>
#include <math.h>

// Problem constants (fixed by setup_inputs)
#define BB 16
#define CC 192
#define TS 2048
#define TT 512
#define KK 384   // 2*CC

// d_out float offsets
#define OFF_PATH 0
#define OFF_DUR  (16777216)
#define OFF_LOGW (OFF_DUR + 8192)
#define OFF_MEXP (OFF_LOGW + 8192)
#define OFF_LEXP (OFF_MEXP + 6291456)
#define OFF_TMASK (OFF_LEXP + 6291456)
#define OFF_SMASK (OFF_TMASK + 8192)

#define NEGCF (-1e9f)

// ---------------------------------------------------------------------------
// prep: per (b,u): s = exp(-2 logs), Bmat rows {m*s, s}, avec = nc1+nc4,
// plus text_mask / spec_mask outputs.
__global__ __launch_bounds__(512) void vits_prep(
    const float* __restrict__ m_p, const float* __restrict__ logs_p,
    const int* __restrict__ spec_len, const int* __restrict__ text_len,
    float* __restrict__ Bmat, float* __restrict__ avec,
    float* __restrict__ tmask, float* __restrict__ smask)
{
    const int b = blockIdx.x;
    const int u = threadIdx.x;
    const float C0 = -0.91893853320467274178f; // -0.5*log(2*pi)
    float a_acc = 0.f;
    for (int c = 0; c < CC; ++c) {
        float lg = logs_p[((size_t)b*CC + c)*TT + u];
        float mm = m_p[((size_t)b*CC + c)*TT + u];
        float s  = expf(-2.f*lg);
        float ms = mm * s;
        Bmat[((size_t)b*KK + 2*c    )*TT + u] = ms;  // pairs with z      -> neg_cent3
        Bmat[((size_t)b*KK + 2*c + 1)*TT + u] = s;   // pairs with -.5z^2 -> neg_cent2
        a_acc += C0 - lg - 0.5f*mm*ms;               // nc1 + nc4 terms
    }
    avec[b*TT + u] = a_acc;
    tmask[b*TT + u] = (u < text_len[b]) ? 1.f : 0.f;
    for (int t = u; t < TS; t += TT)
        smask[b*TS + t] = (t < spec_len[b]) ? 1.f : 0.f;
}

// ---------------------------------------------------------------------------
// gemm: nc[b][t][u] = avec[b][u] + sum_k X[k][t] * Bmat[k][u]
// X[2c][t] = z[b][c][t], X[2c+1][t] = -0.5*z^2. 64x64 tile, 4x4 microtile.
__global__ __launch_bounds__(256) void vits_gemm(
    const float* __restrict__ z, const float* __restrict__ Bmat,
    const float* __restrict__ avec, float* __restrict__ out)
{
    const int b  = blockIdx.z;
    const int t0 = blockIdx.y * 64;
    const int u0 = blockIdx.x * 64;
    __shared__ float As[16][68];
    __shared__ float Bs[16][68];
    const int tid = threadIdx.x;
    const int tx = tid & 15, ty = tid >> 4;
    float acc[4][4] = {};
    const float* zb = z    + (size_t)b * CC * TS;
    const float* Bb = Bmat + (size_t)b * KK * TT;
    for (int kc = 0; kc < KK/16; ++kc) {
        {
            int c_l = tid >> 5;            // 0..7
            int t_l = (tid & 31) * 2;
            const float* zp = zb + (size_t)(kc*8 + c_l)*TS + t0 + t_l;
            float2 zv = *(const float2*)zp;
            float2 z1 = make_float2(zv.x, zv.y);
            float2 z2 = make_float2(-0.5f*zv.x*zv.x, -0.5f*zv.y*zv.y);
            *(float2*)&As[2*c_l  ][t_l] = z1;
            *(float2*)&As[2*c_l+1][t_l] = z2;
            int k_l = tid >> 4;            // 0..15
            int u_l = (tid & 15) * 4;
            const float* bp = Bb + (size_t)(kc*16 + k_l)*TT + u0 + u_l;
            *(float4*)&Bs[k_l][u_l] = *(const float4*)bp;
        }
        __syncthreads();
        #pragma unroll
        for (int kk = 0; kk < 16; ++kk) {
            float4 av = *(const float4*)&As[kk][ty*4];
            float4 bv = *(const float4*)&Bs[kk][tx*4];
            float aa[4] = {av.x, av.y, av.z, av.w};
            float bb[4] = {bv.x, bv.y, bv.z, bv.w};
            #pragma unroll
            for (int i = 0; i < 4; ++i)
                #pragma unroll
                for (int jj = 0; jj < 4; ++jj)
                    acc[i][jj] += aa[i]*bb[jj];
        }
        __syncthreads();
    }
    float4 a4 = *(const float4*)(avec + b*TT + u0 + tx*4);
    float ab[4] = {a4.x, a4.y, a4.z, a4.w};
    #pragma unroll
    for (int i = 0; i < 4; ++i) {
        float4 o;
        o.x = acc[i][0] + ab[0];
        o.y = acc[i][1] + ab[1];
        o.z = acc[i][2] + ab[2];
        o.w = acc[i][3] + ab[3];
        *(float4*)(out + ((size_t)b*TS + t0 + ty*4 + i)*TT + u0 + tx*4) = o;
    }
}

// ---------------------------------------------------------------------------
// DPP full-wave rotate-by-1: lane n <- lane (n-1)&63 (wave_ror:1 = 0x13C).
__device__ __forceinline__ float dpp_ror1_f32(float v) {
    union { float f; int i; } u, r;
    u.f = v;
    r.i = __builtin_amdgcn_update_dpp(0, u.i, 0x13C, 0xF, 0xF, false);
    return r.f;
}

// ---------------------------------------------------------------------------
// dp: forward Viterbi (f32), 16-wave ghost-zone tiling + LDS row staging.
// Wave w: lanes 32-63 own auth columns w*32..w*32+31; lanes 0-31 ghost-copy
// the left wave's columns. col = w*32+lane-32; wave_ror1 provides col-1.
// Ghost lane 0 takes junk that propagates 1 lane/step; ghosts are refreshed
// from qrow2 every CH steps (CH << 32), so auth columns stay exact.
// nc rows are staged into LDS by global_load_lds (16B/lane, 12 wave-instrs
// per 6-row chunk, issued one chunk ahead); the DP step reads ds_read_b32,
// eliminating the per-step scalar-global-load TA bottleneck (R7: ~256cyc/step
// of address-coalescing for 16 scalar wave-loads/step).
// dirs bit-packed per auth col along t (32-t windows), bank-swizzled.
#define DIRS(j,w) dirs[((j)<<6) | ((w) ^ ((j) & 31))]
#define CH 6

__global__ __launch_bounds__(1024, 1) void vits_dp(
    const float* __restrict__ nc,
    const int* __restrict__ spec_len, const int* __restrict__ text_len,
    float* __restrict__ dur, float* __restrict__ logw, int* __restrict__ jt)
{
    __shared__ unsigned int dirs[TT*(TS/32)];   // 128 KB (swizzled)
    __shared__ float stg[2][CH*TT];             // 24 KB staged nc rows
    __shared__ float qrow2[2][TT];              // 4 KB (double-buffered)
    __shared__ int Tr[TT + 1];                  // 2 KB   => ~158 KB total

    const int tid  = threadIdx.x;
    const int lane = tid & 63;
    const int wid  = tid >> 6;
    const int b = blockIdx.x;
    const int SL = spec_len[b], TL = text_len[b];
    const int col = (wid << 5) + lane - 32;      // auth if lane>=32, ghost else
    const bool auth = (lane >= 32);
    const bool w0g  = (wid == 0) && (lane < 32); // pinned-NEG ghost lanes
    const int colL = (col < 0) ? 0 : col;

    float q = (col == 0) ? 0.0f : NEGCF;
    unsigned int bits = 0;

    const float* ncb = nc + (size_t)b*TS*TT;

    // staging assignment: wave w (w<12) stages half-row (r=w>>1, h=w&1)
    const int sr = wid >> 1, sh = wid & 1;
    const int nch = SL / CH;                     // full chunks

    #define STAGE(cnext) do { \
        if (wid < 2*CH) { \
            int ts_ = (cnext)*CH + sr; if (ts_ > SL-1) ts_ = SL-1; \
            const float* src_ = ncb + (size_t)ts_*TT + sh*256 + (lane << 2); \
            __builtin_amdgcn_global_load_lds( \
                (const __attribute__((address_space(1))) unsigned int*)src_, \
                (__attribute__((address_space(3))) unsigned int*)&stg[(cnext)&1][sr*TT + sh*256], \
                16, 0, 0); \
        } } while (0)

    // prologue: stage chunk 0 synchronously
    STAGE(0);
    asm volatile("s_waitcnt vmcnt(0)");
    __syncthreads();

    for (int c = 0; c < nch; ++c) {
        STAGE(c+1);                              // async, lands before next chunk
        const float* lrow = &stg[c & 1][colL];
        float fr[CH];
        #pragma unroll
        for (int r = 0; r < CH; ++r) fr[r] = lrow[r*TT];   // ds_read_b32 x6
        #pragma unroll
        for (int r = 0; r < CH; ++r) {
            const int t = c*CH + r;
            float qp = dpp_ror1_f32(q);          // lane l <- q[col-1]
            bool d = (qp >= q);                  // ref: q_shift >= q
            bits = (bits << 1) | (unsigned)d;
            float qn = fr[r] + fmaxf(qp, q);
            q = w0g ? NEGCF : qn;
            if ((t & 31) == 31) {
                if (auth) DIRS(col, t >> 5) = bits;
                bits = 0;
            }
        }
        if (auth) qrow2[c & 1][col] = q;
        __syncthreads();                         // also drains stage vmcnt
        if (!auth && wid) q = qrow2[c & 1][col]; // ghost refresh
    }
    // tail (SL % CH steps) — direct global loads (few, slow path ok)
    for (int t = nch*CH; t < SL; ++t) {
        float f = ncb[(size_t)t*TT + colL];
        float qp = dpp_ror1_f32(q);
        bool d = (qp >= q);
        bits = (bits << 1) | (unsigned)d;
        float qn = f + fmaxf(qp, q);
        q = w0g ? NEGCF : qn;
        if ((t & 31) == 31) {
            if (auth) DIRS(col, t >> 5) = bits;
            bits = 0;
        }
    }
    if (SL & 31) {
        int w = SL >> 5, r = SL & 31;
        if (auth) DIRS(col, w) = bits << (32 - r);
    }
    __syncthreads();

    for (int i = tid; i <= TT; i += 1024) Tr[i] = 0;
    __syncthreads();

    if (tid == 0) {
        Tr[TL] = SL;
        int j = TL - 1, tc = SL - 1;
        // Tr[j] = first frame aligned to text index j (transition time)
        while (j > 0 && tc >= 0) {
            int w = tc >> 5;
            int bcur = 31 - (tc & 31);
            unsigned int W = DIRS(j, w) & (0xFFFFFFFFu << bcur);
            if (W) {
                int bp = __ffs(W) - 1;          // lowest set bit >= bcur
                int tp = (w << 5) + 31 - bp;    // = largest t' <= tc with d=1
                Tr[j] = tp;
                --j;
                tc = tp - 1;
            } else {
                if (w == 0) break;
                tc = (w << 5) - 1;
            }
        }
    }
    __syncthreads();

    for (int u = tid; u < TT; u += 1024) {
        float dv = (u < TL) ? (float)(Tr[u+1] - Tr[u]) : 0.0f;
        dur[b*TT + u] = dv;
        logw[b*TT + u] = (u < TL) ? logf(dv + 1e-6f) : 0.0f;
    }
    // jt: range-fill [Tr[u], Tr[u+1]) -> u
    for (int u = 0; u < TL; ++u) {
        int t1 = Tr[u+1];
        for (int t = Tr[u] + tid; t < t1; t += 1024) jt[b*TS + t] = u;
    }
    for (int t = SL + tid; t < TS; t += 1024) jt[b*TS + t] = -1;
}

// ---------------------------------------------------------------------------
// path: path[b][t][u] = (u == jt[b][t]) ? 1 : 0   (float4-vectorized)
__global__ void vits_path(const int* __restrict__ jt, float4* __restrict__ path)
{
    int idx = blockIdx.x*blockDim.x + threadIdx.x;
    const int total = BB*TS*(TT/4);
    for (; idx < total; idx += gridDim.x*blockDim.x) {
        int u4 = idx & (TT/4 - 1);
        int bt = idx >> 7;
        int j = jt[bt];
        float4 v = make_float4(0.f,0.f,0.f,0.f);
        int r = j - (u4 << 2);
        if (r >= 0 && r < 4) ((float*)&v)[r] = 1.f;
        path[idx] = v;
    }
}

// ---------------------------------------------------------------------------
// m/logs expansion: out[b][c][t] = (jt>=0) ? src[b][c][jt] : 0
__global__ void vits_mlexp(const int* __restrict__ jt,
    const float* __restrict__ m_p, const float* __restrict__ logs_p,
    float4* __restrict__ mexp, float4* __restrict__ lexp)
{
    int idx = blockIdx.x*blockDim.x + threadIdx.x;
    const int total = BB*CC*(TS/4);
    for (; idx < total; idx += gridDim.x*blockDim.x) {
        int t4 = idx & (TS/4 - 1);
        int bc = idx >> 9;
        int b = bc / CC;
        int4 jv = *(const int4*)(jt + b*TS + (t4 << 2));
        const float* mrow = m_p    + (size_t)bc*TT;
        const float* lrow = logs_p + (size_t)bc*TT;
        float4 mv, lv;
        mv.x = (jv.x >= 0) ? mrow[jv.x] : 0.f;  lv.x = (jv.x >= 0) ? lrow[jv.x] : 0.f;
        mv.y = (jv.y >= 0) ? mrow[jv.y] : 0.f;  lv.y = (jv.y >= 0) ? lrow[jv.y] : 0.f;
        mv.z = (jv.z >= 0) ? mrow[jv.z] : 0.f;  lv.z = (jv.z >= 0) ? lrow[jv.z] : 0.f;
        mv.w = (jv.w >= 0) ? mrow[jv.w] : 0.f;  lv.w = (jv.w >= 0) ? lrow[jv.w] : 0.f;
        mexp[idx] = mv;
        lexp[idx] = lv;
    }
}

// ---------------------------------------------------------------------------
extern "C" void kernel_launch(void* const* d_in, const int* in_sizes, int n_in,
                              void* d_out, int out_size, void* d_ws, size_t ws_size,
                              hipStream_t stream) {
    const float* z_p      = (const float*)d_in[0];
    const float* m_p      = (const float*)d_in[1];
    const float* logs_p   = (const float*)d_in[2];
    const int*   spec_len = (const int*)d_in[3];
    const int*   text_len = (const int*)d_in[4];
    float* out = (float*)d_out;

    float* Bmat = (float*)d_ws;                  // [B][384][512] f32 = 12.6 MB
    float* avec = Bmat + (size_t)BB*KK*TT;       // [B][512]
    int*   jt   = (int*)(avec + BB*TT);          // [B][2048]

    float* path  = out + OFF_PATH;   // doubles as neg_cent staging
    float* dur   = out + OFF_DUR;
    float* logw  = out + OFF_LOGW;
    float* mexp  = out + OFF_MEXP;
    float* lexp  = out + OFF_LEXP;
    float* tmask = out + OFF_TMASK;
    float* smask = out + OFF_SMASK;

    vits_prep<<<BB, 512, 0, stream>>>(m_p, logs_p, spec_len, text_len,
                                      Bmat, avec, tmask, smask);
    vits_gemm<<<dim3(TT/64, TS/64, BB), 256, 0, stream>>>(z_p, Bmat, avec, path);
    vits_dp<<<BB, 1024, 0, stream>>>(path, spec_len, text_len, dur, logw, jt);
    vits_path<<<2048, 256, 0, stream>>>(jt, (float4*)path);
    vits_mlexp<<<2048, 256, 0, stream>>>(jt, m_p, logs_p, (float4*)mexp, (float4*)lexp);
}